// Round 4
// baseline (573.490 us; speedup 1.0000x reference)
//
#include <hip/hip_runtime.h>

constexpr int IN_F = 128;
constexpr int HID  = 64;
constexpr int OUTF = 40;
constexpr int SCAN_CHUNK = 1024;   // elements per scan block (256 thr x 4)

// ---------------- degree counting (int atomics) ----------------
__global__ void deg_kernel(const int* __restrict__ src, const int* __restrict__ dst,
                           int* __restrict__ degi_out, int* __restrict__ degi_in, int E) {
    int stride = gridDim.x * blockDim.x;
    for (int i = blockIdx.x * blockDim.x + threadIdx.x; i < E; i += stride) {
        atomicAdd(&degi_out[src[i]], 1);
        atomicAdd(&degi_in[dst[i]], 1);
    }
}

// ---------------- norms from counts ----------------
__global__ void norm_kernel(const int* __restrict__ degi_out, const int* __restrict__ degi_in,
                            float* __restrict__ norm_out, float* __restrict__ norm_in, int N) {
    int stride = gridDim.x * blockDim.x;
    for (int i = blockIdx.x * blockDim.x + threadIdx.x; i < N; i += stride) {
        norm_out[i] = rsqrtf(fmaxf((float)degi_out[i], 1.0f));
        norm_in[i]  = rsqrtf(fmaxf((float)degi_in[i], 1.0f));
    }
}

// ---------------- exclusive scan of in-degrees (3 kernels) ----------------
__global__ void scan_partial_kernel(const int* __restrict__ degi, int* __restrict__ off,
                                    int* __restrict__ partials, int N) {
    __shared__ int lds[256];
    const int t = threadIdx.x;
    const int i0 = blockIdx.x * SCAN_CHUNK + t * 4;
    int v[4];
    #pragma unroll
    for (int j = 0; j < 4; ++j) v[j] = (i0 + j < N) ? degi[i0 + j] : 0;
    int s = v[0] + v[1] + v[2] + v[3];
    lds[t] = s;
    __syncthreads();
    for (int d = 1; d < 256; d <<= 1) {
        int x = (t >= d) ? lds[t - d] : 0;
        __syncthreads();
        lds[t] += x;
        __syncthreads();
    }
    int run = lds[t] - s;
    if (t == 255) partials[blockIdx.x] = lds[255];
    #pragma unroll
    for (int j = 0; j < 4; ++j) {
        if (i0 + j < N) off[i0 + j] = run;
        run += v[j];
    }
}

__global__ void scan_partials_kernel(int* __restrict__ partials, int nb) {
    if (blockIdx.x == 0 && threadIdx.x == 0) {
        int run = 0;
        for (int i = 0; i < nb; ++i) { int t = partials[i]; partials[i] = run; run += t; }
    }
}

__global__ void scan_add_kernel(int* __restrict__ off, const int* __restrict__ partials,
                                int N, int E) {
    int i = blockIdx.x * blockDim.x + threadIdx.x;
    if (i < N) off[i] += partials[i / SCAN_CHUNK];
    if (i == 0) off[N] = E;
}

// ---------------- CSR fill ----------------
__global__ void fill_csr_kernel(const int* __restrict__ src, const int* __restrict__ dst,
                                const int* __restrict__ off, int* __restrict__ cursor,
                                int* __restrict__ csr_src, int E) {
    int stride = gridDim.x * blockDim.x;
    for (int e = blockIdx.x * blockDim.x + threadIdx.x; e < E; e += stride) {
        int d = dst[e];
        int pos = off[d] + atomicAdd(&cursor[d], 1);
        csr_src[pos] = src[e];
    }
}

// ---------------- gemm1: H1 = (X * norm_out) @ W1  [N,128]@[128,64] ----------------
// 64-node tile; 256 threads; each thread a 4x4 register block.
__global__ __launch_bounds__(256) void gemm1_kernel(const float* __restrict__ X,
        const float* __restrict__ W1, const float* __restrict__ norm_out,
        float* __restrict__ H1, int N) {
    __shared__ float Xs[64][132];               // +4 pad: breaks stride-128 bank alias
    __shared__ float Ws[128][64];
    const int tid = threadIdx.x;
    // stage W1 (8192 floats = 2048 float4)
    for (int i = tid; i < 2048; i += 256) {
        int r = i >> 4, c4 = i & 15;
        *reinterpret_cast<float4*>(&Ws[r][c4 * 4]) = reinterpret_cast<const float4*>(W1)[i];
    }
    const int tile0 = blockIdx.x * 64;
    // stage X tile scaled by norm_out (64 rows x 32 float4)
    for (int i = tid; i < 2048; i += 256) {
        int r = i >> 5, c4 = i & 31;
        int node = tile0 + r;
        float4 v = {0.f, 0.f, 0.f, 0.f};
        float nrm = 0.f;
        if (node < N) {
            v = reinterpret_cast<const float4*>(X + (size_t)node * IN_F)[c4];
            nrm = norm_out[node];
        }
        v.x *= nrm; v.y *= nrm; v.z *= nrm; v.w *= nrm;
        *reinterpret_cast<float4*>(&Xs[r][c4 * 4]) = v;
    }
    __syncthreads();
    const int tr = tid >> 4;                    // 0..15 (node group of 4)
    const int tc = tid & 15;                    // 0..15 (col group of 4)
    float acc[4][4] = {};
    for (int k = 0; k < IN_F; k += 4) {
        float4 a[4];
        #pragma unroll
        for (int i = 0; i < 4; ++i) a[i] = *reinterpret_cast<const float4*>(&Xs[tr * 4 + i][k]);
        #pragma unroll
        for (int kk = 0; kk < 4; ++kk) {
            float4 b = *reinterpret_cast<const float4*>(&Ws[k + kk][tc * 4]);
            #pragma unroll
            for (int i = 0; i < 4; ++i) {
                float av = (kk == 0) ? a[i].x : (kk == 1) ? a[i].y : (kk == 2) ? a[i].z : a[i].w;
                acc[i][0] = fmaf(av, b.x, acc[i][0]);
                acc[i][1] = fmaf(av, b.y, acc[i][1]);
                acc[i][2] = fmaf(av, b.z, acc[i][2]);
                acc[i][3] = fmaf(av, b.w, acc[i][3]);
            }
        }
    }
    #pragma unroll
    for (int i = 0; i < 4; ++i) {
        int node = tile0 + tr * 4 + i;
        if (node < N) {
            float4 o = {acc[i][0], acc[i][1], acc[i][2], acc[i][3]};
            *reinterpret_cast<float4*>(&H1[(size_t)node * HID + tc * 4]) = o;
        }
    }
}

// ---------------- agg1: A1 = relu(segsum(H1)*norm_in + b1) * norm_out ----------------
__global__ __launch_bounds__(256) void agg1_kernel(const float* __restrict__ H1,
        const int* __restrict__ off, const int* __restrict__ csr_src,
        const float* __restrict__ b1, const float* __restrict__ norm_out,
        const float* __restrict__ norm_in, float* __restrict__ A1, int N) {
    const int lane = threadIdx.x & 63;
    const int wave = threadIdx.x >> 6;
    const int node = blockIdx.x * 4 + wave;
    if (node >= N) return;
    const int e0 = off[node], e1 = off[node + 1];
    float acc = 0.f;
    int e = e0;
    for (; e + 4 <= e1; e += 4) {
        int s0 = csr_src[e], s1 = csr_src[e + 1], s2 = csr_src[e + 2], s3 = csr_src[e + 3];
        float v0 = H1[(size_t)s0 * HID + lane];
        float v1 = H1[(size_t)s1 * HID + lane];
        float v2 = H1[(size_t)s2 * HID + lane];
        float v3 = H1[(size_t)s3 * HID + lane];
        acc += (v0 + v1) + (v2 + v3);
    }
    for (; e < e1; ++e) acc += H1[(size_t)csr_src[e] * HID + lane];
    float h = fmaxf(fmaf(acc, norm_in[node], b1[lane]), 0.f) * norm_out[node];
    A1[(size_t)node * HID + lane] = h;
}

// ---------------- gemm2: H2 = A1 @ W2  [N,64]@[64,40] ----------------
// 64-node tile; thread = 2 nodes x 5 cols. W2 transposed in LDS for float4 k-reads.
__global__ __launch_bounds__(256) void gemm2_kernel(const float* __restrict__ A1,
        const float* __restrict__ W2, float* __restrict__ H2, int N) {
    __shared__ float As[64][68];                // pad 68
    __shared__ float W2t[OUTF][68];             // transposed, padded
    const int tid = threadIdx.x;
    // stage W2 transposed (2560 floats)
    for (int i = tid; i < HID * OUTF; i += 256) {
        int k = i / OUTF, c = i - k * OUTF;
        W2t[c][k] = W2[i];
    }
    const int tile0 = blockIdx.x * 64;
    for (int i = tid; i < 1024; i += 256) {     // 64 rows x 16 float4
        int r = i >> 4, c4 = i & 15;
        int node = tile0 + r;
        float4 v = {0.f, 0.f, 0.f, 0.f};
        if (node < N) v = reinterpret_cast<const float4*>(A1 + (size_t)node * HID)[c4];
        *reinterpret_cast<float4*>(&As[r][c4 * 4]) = v;
    }
    __syncthreads();
    const int tr = tid >> 3;                    // 0..31 (node pair)
    const int tc = tid & 7;                     // 0..7 (col group of 5)
    float acc[2][5] = {};
    for (int k = 0; k < HID; k += 4) {
        float4 a0 = *reinterpret_cast<const float4*>(&As[tr * 2 + 0][k]);
        float4 a1 = *reinterpret_cast<const float4*>(&As[tr * 2 + 1][k]);
        #pragma unroll
        for (int j = 0; j < 5; ++j) {
            float4 b = *reinterpret_cast<const float4*>(&W2t[tc * 5 + j][k]);
            acc[0][j] += a0.x * b.x + a0.y * b.y + a0.z * b.z + a0.w * b.w;
            acc[1][j] += a1.x * b.x + a1.y * b.y + a1.z * b.z + a1.w * b.w;
        }
    }
    #pragma unroll
    for (int i = 0; i < 2; ++i) {
        int node = tile0 + tr * 2 + i;
        if (node < N) {
            #pragma unroll
            for (int j = 0; j < 5; ++j)
                H2[(size_t)node * OUTF + tc * 5 + j] = acc[i][j];
        }
    }
}

// ---------------- agg2: out = segsum(H2)*norm_in + b2 ----------------
__global__ __launch_bounds__(256) void agg2_kernel(const float* __restrict__ H2,
        const int* __restrict__ off, const int* __restrict__ csr_src,
        const float* __restrict__ norm_in, const float* __restrict__ b2,
        float* __restrict__ out, int N) {
    const int lane = threadIdx.x & 63;
    const int wave = threadIdx.x >> 6;
    const int node = blockIdx.x * 4 + wave;
    if (node >= N) return;
    const int e0 = off[node], e1 = off[node + 1];
    if (lane < OUTF) {
        float acc = 0.f;
        int e = e0;
        for (; e + 4 <= e1; e += 4) {
            int s0 = csr_src[e], s1 = csr_src[e + 1], s2 = csr_src[e + 2], s3 = csr_src[e + 3];
            float v0 = H2[(size_t)s0 * OUTF + lane];
            float v1 = H2[(size_t)s1 * OUTF + lane];
            float v2 = H2[(size_t)s2 * OUTF + lane];
            float v3 = H2[(size_t)s3 * OUTF + lane];
            acc += (v0 + v1) + (v2 + v3);
        }
        for (; e < e1; ++e) acc += H2[(size_t)csr_src[e] * OUTF + lane];
        out[(size_t)node * OUTF + lane] = fmaf(acc, norm_in[node], b2[lane]);
    }
}

extern "C" void kernel_launch(void* const* d_in, const int* in_sizes, int n_in,
                              void* d_out, int out_size, void* d_ws, size_t ws_size,
                              hipStream_t stream) {
    const float* X   = (const float*)d_in[0];
    const int*   src = (const int*)d_in[1];
    const int*   dst = (const int*)d_in[2];
    const float* W1  = (const float*)d_in[3];
    const float* b1  = (const float*)d_in[4];
    const float* W2  = (const float*)d_in[5];
    const float* b2  = (const float*)d_in[6];
    float* out = (float*)d_out;
    const int N = in_sizes[0] / IN_F;
    const int E = in_sizes[1];

    // workspace layout
    int*   degi_out = (int*)d_ws;                    // N
    int*   degi_in  = degi_out + N;                  // N
    int*   off      = degi_in + N;                   // N+1
    int*   cursor   = off + N + 1;                   // N
    int*   partials = cursor + N;                    // 256
    int*   csr_src  = partials + 256;                // E
    float* norm_out = (float*)(csr_src + E);         // N
    float* norm_in  = norm_out + N;                  // N
    float* H1       = norm_in + N;                   // N*HID
    float* A1       = H1 + (size_t)N * HID;          // N*HID
    float* H2       = A1 + (size_t)N * HID;          // N*OUTF

    const int nb = (N + SCAN_CHUNK - 1) / SCAN_CHUNK;

    hipMemsetAsync(degi_out, 0, sizeof(int) * 2 * (size_t)N, stream);
    hipMemsetAsync(cursor,   0, sizeof(int) * (size_t)N, stream);

    int degBlocks = (E + 255) / 256; if (degBlocks > 2048) degBlocks = 2048;
    deg_kernel<<<degBlocks, 256, 0, stream>>>(src, dst, degi_out, degi_in, E);
    norm_kernel<<<(N + 255) / 256, 256, 0, stream>>>(degi_out, degi_in, norm_out, norm_in, N);
    scan_partial_kernel<<<nb, 256, 0, stream>>>(degi_in, off, partials, N);
    scan_partials_kernel<<<1, 64, 0, stream>>>(partials, nb);
    scan_add_kernel<<<(N + 255) / 256, 256, 0, stream>>>(off, partials, N, E);
    fill_csr_kernel<<<degBlocks, 256, 0, stream>>>(src, dst, off, cursor, csr_src, E);

    const int ntiles = (N + 63) / 64;
    gemm1_kernel<<<ntiles, 256, 0, stream>>>(X, W1, norm_out, H1, N);
    agg1_kernel<<<(N + 3) / 4, 256, 0, stream>>>(H1, off, csr_src, b1, norm_out, norm_in, A1, N);
    gemm2_kernel<<<ntiles, 256, 0, stream>>>(A1, W2, H2, N);
    agg2_kernel<<<(N + 3) / 4, 256, 0, stream>>>(H2, off, csr_src, norm_in, b2, out, N);
}

// Round 16
// 275.726 us; speedup vs baseline: 2.0799x; 2.0799x over previous
//
#include <hip/hip_runtime.h>

constexpr int IN_F = 128;
constexpr int HID  = 64;
constexpr int OUTF = 40;
constexpr int SCAN_CHUNK = 1024;   // elements per scan block (256 thr x 4)

// ---------------- degree counting (int atomics) ----------------
__global__ void deg_kernel(const int* __restrict__ src, const int* __restrict__ dst,
                           int* __restrict__ degi_out, int* __restrict__ degi_in, int E) {
    int stride = gridDim.x * blockDim.x;
    for (int i = blockIdx.x * blockDim.x + threadIdx.x; i < E; i += stride) {
        atomicAdd(&degi_out[src[i]], 1);
        atomicAdd(&degi_in[dst[i]], 1);
    }
}

// ---------------- norms from counts ----------------
__global__ void norm_kernel(const int* __restrict__ degi_out, const int* __restrict__ degi_in,
                            float* __restrict__ norm_out, float* __restrict__ norm_in, int N) {
    int stride = gridDim.x * blockDim.x;
    for (int i = blockIdx.x * blockDim.x + threadIdx.x; i < N; i += stride) {
        norm_out[i] = rsqrtf(fmaxf((float)degi_out[i], 1.0f));
        norm_in[i]  = rsqrtf(fmaxf((float)degi_in[i], 1.0f));
    }
}

// ---------------- exclusive scan of in-degrees (3 kernels) ----------------
__global__ void scan_partial_kernel(const int* __restrict__ degi, int* __restrict__ off,
                                    int* __restrict__ partials, int N) {
    __shared__ int lds[256];
    const int t = threadIdx.x;
    const int i0 = blockIdx.x * SCAN_CHUNK + t * 4;
    int v[4];
    #pragma unroll
    for (int j = 0; j < 4; ++j) v[j] = (i0 + j < N) ? degi[i0 + j] : 0;
    int s = v[0] + v[1] + v[2] + v[3];
    lds[t] = s;
    __syncthreads();
    for (int d = 1; d < 256; d <<= 1) {
        int x = (t >= d) ? lds[t - d] : 0;
        __syncthreads();
        lds[t] += x;
        __syncthreads();
    }
    int run = lds[t] - s;
    if (t == 255) partials[blockIdx.x] = lds[255];
    #pragma unroll
    for (int j = 0; j < 4; ++j) {
        if (i0 + j < N) off[i0 + j] = run;
        run += v[j];
    }
}

__global__ void scan_partials_kernel(int* __restrict__ partials, int nb) {
    if (blockIdx.x == 0 && threadIdx.x == 0) {
        int run = 0;
        for (int i = 0; i < nb; ++i) { int t = partials[i]; partials[i] = run; run += t; }
    }
}

__global__ void scan_add_kernel(int* __restrict__ off, const int* __restrict__ partials,
                                int N, int E) {
    int i = blockIdx.x * blockDim.x + threadIdx.x;
    if (i < N) off[i] += partials[i / SCAN_CHUNK];
    if (i == 0) off[N] = E;
}

// ---------------- CSR fill ----------------
__global__ void fill_csr_kernel(const int* __restrict__ src, const int* __restrict__ dst,
                                const int* __restrict__ off, int* __restrict__ cursor,
                                int* __restrict__ csr_src, int E) {
    int stride = gridDim.x * blockDim.x;
    for (int e = blockIdx.x * blockDim.x + threadIdx.x; e < E; e += stride) {
        int d = dst[e];
        int pos = off[d] + atomicAdd(&cursor[d], 1);
        csr_src[pos] = src[e];
    }
}

// ---------------- gemm1: H1 = norm_out * (X @ W1)  [N,128]@[128,64] ----------------
// 64-node tile, K-tiled at 32. 256 threads; thread = 4 nodes x 4 cols.
// LDS 17.9 KB; k-loop explicitly bounded (#pragma unroll 2) to avoid the
// round-4 full-unroll VGPR spill (VGPR=256, 780 MB scratch traffic).
__global__ __launch_bounds__(256) void gemm1_kernel(const float* __restrict__ X,
        const float* __restrict__ W1, const float* __restrict__ norm_out,
        float* __restrict__ H1, int N) {
    constexpr int KT = 32;
    __shared__ float Xs[64][KT + 4];            // 9.2 KB, row stride 144 B
    __shared__ float Ws[KT][HID + 4];           // 8.7 KB, row stride 272 B
    const int tid = threadIdx.x;
    const int tile0 = blockIdx.x * 64;
    const int tr = tid >> 4;                    // 0..15 (node group of 4)
    const int tc = tid & 15;                    // 0..15 (col group of 4)
    float acc[4][4] = {};
    for (int kt = 0; kt < IN_F; kt += KT) {
        // stage X tile: 64 rows x 32 k = 512 float4
        for (int i = tid; i < 512; i += 256) {
            int r = i >> 3, c4 = i & 7;
            int node = tile0 + r;
            float4 v = {0.f, 0.f, 0.f, 0.f};
            if (node < N)
                v = *reinterpret_cast<const float4*>(X + (size_t)node * IN_F + kt + c4 * 4);
            *reinterpret_cast<float4*>(&Xs[r][c4 * 4]) = v;
        }
        // stage W1 tile: 32 rows x 64 cols = 512 float4
        for (int i = tid; i < 512; i += 256) {
            int r = i >> 4, c4 = i & 15;
            float4 v = *reinterpret_cast<const float4*>(W1 + (size_t)(kt + r) * HID + c4 * 4);
            *reinterpret_cast<float4*>(&Ws[r][c4 * 4]) = v;
        }
        __syncthreads();
        #pragma unroll 2
        for (int k4 = 0; k4 < KT; k4 += 4) {
            float4 a[4];
            #pragma unroll
            for (int i = 0; i < 4; ++i)
                a[i] = *reinterpret_cast<const float4*>(&Xs[tr * 4 + i][k4]);
            #pragma unroll
            for (int kk = 0; kk < 4; ++kk) {
                float4 b = *reinterpret_cast<const float4*>(&Ws[k4 + kk][tc * 4]);
                #pragma unroll
                for (int i = 0; i < 4; ++i) {
                    float av = (kk == 0) ? a[i].x : (kk == 1) ? a[i].y : (kk == 2) ? a[i].z : a[i].w;
                    acc[i][0] = fmaf(av, b.x, acc[i][0]);
                    acc[i][1] = fmaf(av, b.y, acc[i][1]);
                    acc[i][2] = fmaf(av, b.z, acc[i][2]);
                    acc[i][3] = fmaf(av, b.w, acc[i][3]);
                }
            }
        }
        __syncthreads();
    }
    #pragma unroll
    for (int i = 0; i < 4; ++i) {
        int node = tile0 + tr * 4 + i;
        if (node < N) {
            float nrm = norm_out[node];      // (x*n)@W == n*(x@W): scale once here
            float4 o = {acc[i][0] * nrm, acc[i][1] * nrm, acc[i][2] * nrm, acc[i][3] * nrm};
            *reinterpret_cast<float4*>(&H1[(size_t)node * HID + tc * 4]) = o;
        }
    }
}

// ---------------- agg1: A1 = relu(segsum(H1)*norm_in + b1) * norm_out ----------------
__global__ __launch_bounds__(256) void agg1_kernel(const float* __restrict__ H1,
        const int* __restrict__ off, const int* __restrict__ csr_src,
        const float* __restrict__ b1, const float* __restrict__ norm_out,
        const float* __restrict__ norm_in, float* __restrict__ A1, int N) {
    const int lane = threadIdx.x & 63;
    const int wave = threadIdx.x >> 6;
    const int node = blockIdx.x * 4 + wave;
    if (node >= N) return;
    const int e0 = off[node], e1 = off[node + 1];
    float acc = 0.f;
    int e = e0;
    for (; e + 4 <= e1; e += 4) {
        int s0 = csr_src[e], s1 = csr_src[e + 1], s2 = csr_src[e + 2], s3 = csr_src[e + 3];
        float v0 = H1[(size_t)s0 * HID + lane];
        float v1 = H1[(size_t)s1 * HID + lane];
        float v2 = H1[(size_t)s2 * HID + lane];
        float v3 = H1[(size_t)s3 * HID + lane];
        acc += (v0 + v1) + (v2 + v3);
    }
    for (; e < e1; ++e) acc += H1[(size_t)csr_src[e] * HID + lane];
    float h = fmaxf(fmaf(acc, norm_in[node], b1[lane]), 0.f) * norm_out[node];
    A1[(size_t)node * HID + lane] = h;
}

// ---------------- gemm2: H2 = A1 @ W2  [N,64]@[64,40] ----------------
// 64-node tile; thread = 2 nodes x 5 cols. W2 transposed in LDS for float4 k-reads.
__global__ __launch_bounds__(256) void gemm2_kernel(const float* __restrict__ A1,
        const float* __restrict__ W2, float* __restrict__ H2, int N) {
    __shared__ float As[64][68];                // pad 68
    __shared__ float W2t[OUTF][68];             // transposed, padded
    const int tid = threadIdx.x;
    for (int i = tid; i < HID * OUTF; i += 256) {
        int k = i / OUTF, c = i - k * OUTF;
        W2t[c][k] = W2[i];
    }
    const int tile0 = blockIdx.x * 64;
    for (int i = tid; i < 1024; i += 256) {     // 64 rows x 16 float4
        int r = i >> 4, c4 = i & 15;
        int node = tile0 + r;
        float4 v = {0.f, 0.f, 0.f, 0.f};
        if (node < N) v = reinterpret_cast<const float4*>(A1 + (size_t)node * HID)[c4];
        *reinterpret_cast<float4*>(&As[r][c4 * 4]) = v;
    }
    __syncthreads();
    const int tr = tid >> 3;                    // 0..31 (node pair)
    const int tc = tid & 7;                     // 0..7 (col group of 5)
    float acc[2][5] = {};
    #pragma unroll 4
    for (int k = 0; k < HID; k += 4) {
        float4 a0 = *reinterpret_cast<const float4*>(&As[tr * 2 + 0][k]);
        float4 a1 = *reinterpret_cast<const float4*>(&As[tr * 2 + 1][k]);
        #pragma unroll
        for (int j = 0; j < 5; ++j) {
            float4 b = *reinterpret_cast<const float4*>(&W2t[tc * 5 + j][k]);
            acc[0][j] += a0.x * b.x + a0.y * b.y + a0.z * b.z + a0.w * b.w;
            acc[1][j] += a1.x * b.x + a1.y * b.y + a1.z * b.z + a1.w * b.w;
        }
    }
    #pragma unroll
    for (int i = 0; i < 2; ++i) {
        int node = tile0 + tr * 2 + i;
        if (node < N) {
            #pragma unroll
            for (int j = 0; j < 5; ++j)
                H2[(size_t)node * OUTF + tc * 5 + j] = acc[i][j];
        }
    }
}

// ---------------- agg2: out = segsum(H2)*norm_in + b2 ----------------
__global__ __launch_bounds__(256) void agg2_kernel(const float* __restrict__ H2,
        const int* __restrict__ off, const int* __restrict__ csr_src,
        const float* __restrict__ norm_in, const float* __restrict__ b2,
        float* __restrict__ out, int N) {
    const int lane = threadIdx.x & 63;
    const int wave = threadIdx.x >> 6;
    const int node = blockIdx.x * 4 + wave;
    if (node >= N) return;
    const int e0 = off[node], e1 = off[node + 1];
    if (lane < OUTF) {
        float acc = 0.f;
        int e = e0;
        for (; e + 4 <= e1; e += 4) {
            int s0 = csr_src[e], s1 = csr_src[e + 1], s2 = csr_src[e + 2], s3 = csr_src[e + 3];
            float v0 = H2[(size_t)s0 * OUTF + lane];
            float v1 = H2[(size_t)s1 * OUTF + lane];
            float v2 = H2[(size_t)s2 * OUTF + lane];
            float v3 = H2[(size_t)s3 * OUTF + lane];
            acc += (v0 + v1) + (v2 + v3);
        }
        for (; e < e1; ++e) acc += H2[(size_t)csr_src[e] * OUTF + lane];
        out[(size_t)node * OUTF + lane] = fmaf(acc, norm_in[node], b2[lane]);
    }
}

extern "C" void kernel_launch(void* const* d_in, const int* in_sizes, int n_in,
                              void* d_out, int out_size, void* d_ws, size_t ws_size,
                              hipStream_t stream) {
    const float* X   = (const float*)d_in[0];
    const int*   src = (const int*)d_in[1];
    const int*   dst = (const int*)d_in[2];
    const float* W1  = (const float*)d_in[3];
    const float* b1  = (const float*)d_in[4];
    const float* W2  = (const float*)d_in[5];
    const float* b2  = (const float*)d_in[6];
    float* out = (float*)d_out;
    const int N = in_sizes[0] / IN_F;
    const int E = in_sizes[1];

    // workspace layout
    int*   degi_out = (int*)d_ws;                    // N
    int*   degi_in  = degi_out + N;                  // N
    int*   off      = degi_in + N;                   // N+1
    int*   cursor   = off + N + 1;                   // N
    int*   partials = cursor + N;                    // 256
    int*   csr_src  = partials + 256;                // E
    float* norm_out = (float*)(csr_src + E);         // N
    float* norm_in  = norm_out + N;                  // N
    float* H1       = norm_in + N;                   // N*HID
    float* A1       = H1 + (size_t)N * HID;          // N*HID
    float* H2       = A1 + (size_t)N * HID;          // N*OUTF

    const int nb = (N + SCAN_CHUNK - 1) / SCAN_CHUNK;

    hipMemsetAsync(degi_out, 0, sizeof(int) * 2 * (size_t)N, stream);
    hipMemsetAsync(cursor,   0, sizeof(int) * (size_t)N, stream);

    int degBlocks = (E + 255) / 256; if (degBlocks > 2048) degBlocks = 2048;
    deg_kernel<<<degBlocks, 256, 0, stream>>>(src, dst, degi_out, degi_in, E);
    norm_kernel<<<(N + 255) / 256, 256, 0, stream>>>(degi_out, degi_in, norm_out, norm_in, N);
    scan_partial_kernel<<<nb, 256, 0, stream>>>(degi_in, off, partials, N);
    scan_partials_kernel<<<1, 64, 0, stream>>>(partials, nb);
    scan_add_kernel<<<(N + 255) / 256, 256, 0, stream>>>(off, partials, N, E);
    fill_csr_kernel<<<degBlocks, 256, 0, stream>>>(src, dst, off, cursor, csr_src, E);

    const int ntiles = (N + 63) / 64;
    gemm1_kernel<<<ntiles, 256, 0, stream>>>(X, W1, norm_out, H1, N);
    agg1_kernel<<<(N + 3) / 4, 256, 0, stream>>>(H1, off, csr_src, b1, norm_out, norm_in, A1, N);
    gemm2_kernel<<<ntiles, 256, 0, stream>>>(A1, W2, H2, N);
    agg2_kernel<<<(N + 3) / 4, 256, 0, stream>>>(H2, off, csr_src, norm_in, b2, out, N);
}